// Round 1
// baseline (999.206 us; speedup 1.0000x reference)
//
#include <hip/hip_runtime.h>
#include <hip/hip_bf16.h>

// ---------------- problem constants ----------------
#define EPS_OT   0.1f
#define INV_EPS  10.0f
#define TAU_OT   0.005f
#define NEG_K    -10000000.0f   /* NEG/EPSILON = -1e6/0.1 */
#define DELTA_OT 1e-9f

constexpr int BB  = 64;
constexpr int NV  = 512;
constexpr int NT  = 512;
constexpr int DIM = 768;
constexpr int NA  = 513;              // augmented size
constexpr int KP  = 516;              // K row pitch (floats), 16B-aligned rows
constexpr long KBATCH = (long)NA * KP;

// ---------------- workspace layout (float units) ----------------
constexpr size_t OFF_U     = 0;                     // 64*513
constexpr size_t OFF_VV    = OFF_U     + 64*513;    // 64*513
constexpr size_t OFF_WT    = OFF_VV    + 64*513;    // 64*512
constexpr size_t OFF_LOSS  = OFF_WT    + 64*512;    // 64 (use [0])
constexpr size_t ZERO_FLOATS = OFF_LOSS + 64;       // region zeroed each call
constexpr size_t OFF_LOGMU = ZERO_FLOATS;           // 64*513
constexpr size_t OFF_LOGNU = OFF_LOGMU + 64*513;
constexpr size_t OFF_INVV  = OFF_LOGNU + 64*513;    // 64*512
constexpr size_t OFF_INVT  = OFF_INVV  + 64*512;
constexpr size_t OFF_MASKV = OFF_INVT  + 64*512;    // int 64*512
constexpr size_t OFF_MASKT = OFF_MASKV + 64*512;
constexpr size_t OFF_WV    = OFF_MASKT + 64*512;    // 64*512
constexpr size_t OFF_K     = OFF_WV    + 64*512;    // 64*513*516

// ---------------- mask dtype detection ----------------
__device__ inline int detect_mode(const unsigned char* p) {
    unsigned char b0 = p[0], b1 = p[1];
    if (b0 == 0) return 2;          // float32 (1.0f -> bytes 00 00 80 3F)
    return (b1 != 0) ? 0 : 1;       // 0: u8/bool, 1: int32
}
__device__ inline int read_mask(const unsigned char* p, long idx, int mode) {
    if (mode == 0) return p[idx] != 0;
    if (mode == 1) return p[4*idx] != 0;
    return ((const float*)p)[idx] != 0.0f;
}

// ---------------- setup: masks, lengths, log_mu/log_nu ----------------
__global__ void setup_kernel(const unsigned char* vm, const unsigned char* tm,
                             float* log_mu, float* log_nu, int* maskv, int* maskt) {
    int b = blockIdx.x;
    bool isV = (blockIdx.y == 0);
    const unsigned char* p = isV ? vm : tm;
    float* lg = isV ? log_mu : log_nu;
    int*   mk = isV ? maskv : maskt;
    int mode = detect_mode(p);
    int i = threadIdx.x;                       // 512 threads
    int m = read_mask(p, (long)b*512 + i, mode);
    mk[b*512 + i] = m;
    float s = (float)m;
    #pragma unroll
    for (int off = 32; off; off >>= 1) s += __shfl_xor(s, off);
    __shared__ float wsum[8];
    int wid = threadIdx.x >> 6, lane = threadIdx.x & 63;
    if (lane == 0) wsum[wid] = s;
    __syncthreads();
    float len = 0.f;
    #pragma unroll
    for (int w = 0; w < 8; ++w) len += wsum[w];
    float lm = m ? __logf(1.0f/(len + 1e-9f) + 1e-9f) : __logf(1e-9f);
    lg[b*NA + i] = lm;
    if (i == 0) lg[b*NA + 512] = 0.0f;         // log(1+1e-9) == 0 in fp32
}

// ---------------- row l2 inverse norms ----------------
__global__ __launch_bounds__(256) void norm_kernel(const float* v, const float* t,
                                                   float* invnv, float* invnt) {
    int wid = threadIdx.x >> 6, lane = threadIdx.x & 63;
    long row = (long)blockIdx.x * 4 + wid;        // 0..32767
    const float* src = blockIdx.y ? t : v;
    float* dst = blockIdx.y ? invnt : invnv;
    const float* r = src + row * DIM;
    float ss = 0.f;
    #pragma unroll
    for (int c = 0; c < 3; ++c) {
        float4 x = *(const float4*)(r + (c*64 + lane)*4);
        ss += x.x*x.x + x.y*x.y + x.z*x.z + x.w*x.w;
    }
    #pragma unroll
    for (int off = 32; off; off >>= 1) ss += __shfl_xor(ss, off);
    if (lane == 0) dst[row] = 1.0f / fmaxf(sqrtf(ss), 1e-12f);
}

// ---------------- batched GEMM: K = (v·t^T)*invn*invn/EPS with masking ----------------
__global__ __launch_bounds__(256) void gemm_kernel(const float* v, const float* t,
        const float* invnv, const float* invnt, const int* maskv, const int* maskt,
        float* K) {
    int bt = blockIdx.z;
    int m0 = blockIdx.y * 128, n0 = blockIdx.x * 128;
    __shared__ float As[16][128];
    __shared__ float Bs[16][128];
    const float* vb = v + (long)bt * NV * DIM;
    const float* tb = t + (long)bt * NT * DIM;
    float acc[8][8] = {};
    int tid = threadIdx.x;
    int tx = tid & 15, ty = tid >> 4;

    for (int kt = 0; kt < DIM/16; ++kt) {
        int k0 = kt * 16;
        float4 av[2], bv[2];
        #pragma unroll
        for (int h = 0; h < 2; ++h) {
            int f = tid + h*256;
            int row = f >> 2, c4 = (f & 3) << 2;
            av[h] = *(const float4*)(vb + (long)(m0 + row)*DIM + k0 + c4);
            bv[h] = *(const float4*)(tb + (long)(n0 + row)*DIM + k0 + c4);
        }
        __syncthreads();
        #pragma unroll
        for (int h = 0; h < 2; ++h) {
            int f = tid + h*256;
            int row = f >> 2, c4 = (f & 3) << 2;
            float ta[4], tb4[4];
            *(float4*)ta  = av[h];
            *(float4*)tb4 = bv[h];
            #pragma unroll
            for (int q = 0; q < 4; ++q) { As[c4+q][row] = ta[q]; Bs[c4+q][row] = tb4[q]; }
        }
        __syncthreads();
        for (int k = 0; k < 16; ++k) {
            float af[8], bf[8];
            *(float4*)&af[0] = *(const float4*)&As[k][ty*4];
            *(float4*)&af[4] = *(const float4*)&As[k][ty*4 + 64];
            *(float4*)&bf[0] = *(const float4*)&Bs[k][tx*4];
            *(float4*)&bf[4] = *(const float4*)&Bs[k][tx*4 + 64];
            #pragma unroll
            for (int i = 0; i < 8; ++i)
                #pragma unroll
                for (int j = 0; j < 8; ++j)
                    acc[i][j] += af[i] * bf[j];
        }
    }

    const float* invnv_b = invnv + bt*NV;
    const float* invnt_b = invnt + bt*NT;
    const int*   maskv_b = maskv + bt*NV;
    const int*   maskt_b = maskt + bt*NT;
    float* Kb = K + (long)bt * KBATCH;

    float itv[8]; int mtv[8];
    #pragma unroll
    for (int j = 0; j < 8; ++j) {
        int n = n0 + (j & 3) + tx*4 + (j >> 2)*64;
        itv[j] = invnt_b[n]; mtv[j] = maskt_b[n];
    }
    #pragma unroll
    for (int i = 0; i < 8; ++i) {
        int m = m0 + (i & 3) + ty*4 + (i >> 2)*64;
        float iv = invnv_b[m]; int mv = maskv_b[m];
        float res[8];
        #pragma unroll
        for (int j = 0; j < 8; ++j) {
            float val = acc[i][j] * iv * itv[j] * INV_EPS;
            res[j] = (mv && mtv[j]) ? val : NEG_K;
        }
        float* Kr = Kb + (long)m * KP + n0 + tx*4;
        *(float4*)&Kr[0]  = *(float4*)&res[0];
        *(float4*)&Kr[64] = *(float4*)&res[4];
    }
}

// ---------------- gamma row/col fill: K = GAMMA/EPS = 1.0 ----------------
__global__ void fill_gamma(float* K) {
    int b = blockIdx.x;
    float* Kb = K + (long)b * KBATCH;
    for (int i = threadIdx.x; i < NA; i += blockDim.x) {
        Kb[(long)512*KP + i] = 1.0f;
        Kb[(long)i*KP + 512] = 1.0f;
    }
}

// ---------------- Sinkhorn row pass: u = log_mu - lse_j(K + vv) ----------------
__global__ __launch_bounds__(256) void row_pass(const float* K, const float* vv,
                                                const float* log_mu, float* u) {
    int b = blockIdx.y;
    __shared__ float vvs[NA];
    for (int idx = threadIdx.x; idx < NA; idx += 256) vvs[idx] = vv[b*NA + idx];
    __syncthreads();
    int wid = threadIdx.x >> 6, lane = threadIdx.x & 63;
    const float* Kb = K + (long)b * KBATCH;
    for (int r = 0; r < 4; ++r) {
        int i = blockIdx.x*16 + wid*4 + r;
        if (i >= NA) break;
        const float* Krow = Kb + (long)i * KP;
        float m = -1e30f, s = 0.f;
        #pragma unroll
        for (int c = 0; c < 9; ++c) {
            int j = c*64 + lane;
            if (j < NA) {
                float x = Krow[j] + vvs[j];
                float nm = fmaxf(m, x);
                s = s*__expf(m - nm) + __expf(x - nm);
                m = nm;
            }
        }
        #pragma unroll
        for (int off = 32; off; off >>= 1) {
            float m2 = __shfl_xor(m, off), s2 = __shfl_xor(s, off);
            float nm = fmaxf(m, m2);
            s = s*__expf(m - nm) + s2*__expf(m2 - nm);
            m = nm;
        }
        if (lane == 0) u[b*NA + i] = log_mu[b*NA + i] - (m + __logf(s));
    }
}

// ---------------- Sinkhorn col pass: vv = log_nu - lse_i(K + u) ----------------
__global__ __launch_bounds__(128) void col_pass(const float* K, const float* u,
                                                const float* log_nu, float* vv) {
    int b = blockIdx.y;
    __shared__ float us[NA];
    for (int idx = threadIdx.x; idx < NA; idx += 128) us[idx] = u[b*NA + idx];
    __syncthreads();
    int j = blockIdx.x*128 + threadIdx.x;
    if (j >= NA) return;
    const float* Kb = K + (long)b * KBATCH;
    float m = -1e30f, s = 0.f;
    for (int i = 0; i < NA; ++i) {
        float x = Kb[(long)i*KP + j] + us[i];
        float nm = fmaxf(m, x);
        s = s*__expf(m - nm) + __expf(x - nm);
        m = nm;
    }
    vv[b*NA + j] = log_nu[b*NA + j] - (m + __logf(s));
}

// ---------------- final: T*, loss, row/col sums of relu(T - tau) ----------------
__global__ __launch_bounds__(256) void final_kernel(const float* K, const float* u,
        const float* vv, float* w_v_num, float* w_t_num, float* loss_sum) {
    int b = blockIdx.y;
    __shared__ float vvs[NA];
    __shared__ float colsum[NT];
    __shared__ float lw[4];
    for (int idx = threadIdx.x; idx < NA; idx += 256) vvs[idx] = vv[b*NA + idx];
    for (int idx = threadIdx.x; idx < NT; idx += 256) colsum[idx] = 0.f;
    __syncthreads();
    int wid = threadIdx.x >> 6, lane = threadIdx.x & 63;
    const float* Kb = K + (long)b * KBATCH;
    float colreg[8] = {0,0,0,0,0,0,0,0};
    float lossacc = 0.f;
    for (int r = 0; r < 16; ++r) {
        int i = blockIdx.x*64 + wid*16 + r;
        if (i >= NA) break;
        float ui = u[b*NA + i];
        const float* Krow = Kb + (long)i * KP;
        float rowacc = 0.f;
        bool realrow = (i < NV);
        #pragma unroll
        for (int c = 0; c < 9; ++c) {
            int j = c*64 + lane;
            if (j < NA) {
                float kv = Krow[j];
                float tst = __expf(ui + vvs[j] + kv);
                lossacc += tst * (1.0f - EPS_OT * kv);
                if (realrow && j < NT) {
                    float th = fmaxf(tst - TAU_OT, 0.f);
                    rowacc += th;
                    colreg[c] += th;
                }
            }
        }
        #pragma unroll
        for (int off = 32; off; off >>= 1) rowacc += __shfl_xor(rowacc, off);
        if (realrow && lane == 0) w_v_num[b*NV + i] = rowacc + DELTA_OT;
    }
    #pragma unroll
    for (int c = 0; c < 8; ++c) atomicAdd(&colsum[c*64 + lane], colreg[c]);
    __syncthreads();
    for (int idx = threadIdx.x; idx < NT; idx += 256)
        atomicAdd(&w_t_num[b*NT + idx], colsum[idx]);
    #pragma unroll
    for (int off = 32; off; off >>= 1) lossacc += __shfl_xor(lossacc, off);
    if (lane == 0) lw[wid] = lossacc;
    __syncthreads();
    if (threadIdx.x == 0) atomicAdd(loss_sum, lw[0] + lw[1] + lw[2] + lw[3]);
}

// ---------------- normalize w vectors ----------------
__global__ void wnorm_kernel(const float* num, float* out, float addd) {
    int b = blockIdx.x;
    float v = num[b*512 + threadIdx.x] + addd;
    float s = v;
    #pragma unroll
    for (int off = 32; off; off >>= 1) s += __shfl_xor(s, off);
    __shared__ float wsum[8];
    int wid = threadIdx.x >> 6, lane = threadIdx.x & 63;
    if (lane == 0) wsum[wid] = s;
    __syncthreads();
    float tot = 0.f;
    #pragma unroll
    for (int w = 0; w < 8; ++w) tot += wsum[w];
    out[b*512 + threadIdx.x] = v / tot;
}

__global__ void loss_kernel(const float* loss_sum, float* out) {
    out[0] = loss_sum[0] * (1.0f / 64.0f);
}

// ---------------- launch ----------------
extern "C" void kernel_launch(void* const* d_in, const int* in_sizes, int n_in,
                              void* d_out, int out_size, void* d_ws, size_t ws_size,
                              hipStream_t stream) {
    const float* v = (const float*)d_in[0];
    const float* t = (const float*)d_in[1];
    const unsigned char* vm = (const unsigned char*)d_in[2];
    const unsigned char* tm = (const unsigned char*)d_in[3];
    float* ws  = (float*)d_ws;
    float* out = (float*)d_out;

    float* U     = ws + OFF_U;
    float* VVv   = ws + OFF_VV;
    float* WT    = ws + OFF_WT;
    float* LOSS  = ws + OFF_LOSS;
    float* LOGMU = ws + OFF_LOGMU;
    float* LOGNU = ws + OFF_LOGNU;
    float* INVV  = ws + OFF_INVV;
    float* INVT  = ws + OFF_INVT;
    int*   MASKV = (int*)(ws + OFF_MASKV);
    int*   MASKT = (int*)(ws + OFF_MASKT);
    float* WV    = ws + OFF_WV;
    float* Kmat  = ws + OFF_K;

    hipMemsetAsync(ws, 0, ZERO_FLOATS * sizeof(float), stream);

    setup_kernel<<<dim3(BB, 2), 512, 0, stream>>>(vm, tm, LOGMU, LOGNU, MASKV, MASKT);
    norm_kernel<<<dim3(BB*NV/4, 2), 256, 0, stream>>>(v, t, INVV, INVT);
    gemm_kernel<<<dim3(4, 4, BB), 256, 0, stream>>>(v, t, INVV, INVT, MASKV, MASKT, Kmat);
    fill_gamma<<<BB, 256, 0, stream>>>(Kmat);

    for (int it = 0; it < 5; ++it) {
        row_pass<<<dim3(33, BB), 256, 0, stream>>>(Kmat, VVv, LOGMU, U);
        col_pass<<<dim3(5, BB), 128, 0, stream>>>(Kmat, U, LOGNU, VVv);
    }

    final_kernel<<<dim3(9, BB), 256, 0, stream>>>(Kmat, U, VVv, WV, WT, LOSS);
    wnorm_kernel<<<BB, 512, 0, stream>>>(WV, out + 1, 0.0f);
    wnorm_kernel<<<BB, 512, 0, stream>>>(WT, out + 1 + BB*NV, DELTA_OT);
    loss_kernel<<<1, 1, 0, stream>>>(LOSS, out);
}

// Round 2
// 481.654 us; speedup vs baseline: 2.0745x; 2.0745x over previous
//
#include <hip/hip_runtime.h>
#include <hip/hip_bf16.h>
#include <hip/hip_fp16.h>

// ---------------- problem constants ----------------
#define EPS_OT   0.1f
#define INV_EPS  10.0f
#define TAU_OT   0.005f
#define NEG_KH   -60000.0f      /* masked K sentinel (fits fp16; exp -> exact 0) */
#define DELTA_OT 1e-9f

constexpr int BB  = 64;
constexpr int NV  = 512;
constexpr int NT  = 512;
constexpr int DIM = 768;
constexpr int NA  = 513;              // augmented size
constexpr int KP_H = 520;             // K row pitch in halves (1040B, 16B-aligned)
constexpr long KBATCH_H = (long)NA * KP_H;

// ---------------- workspace layout (float units) ----------------
constexpr size_t OFF_U     = 0;                       // 64*513
constexpr size_t OFF_VV    = OFF_U     + 64*513;      // 64*513 (must start at 0)
constexpr size_t OFF_WT    = OFF_VV    + 64*513;      // 64*512 (atomic accum)
constexpr size_t OFF_LOSS  = OFF_WT    + 64*512;      // 64
constexpr size_t ZERO_FLOATS = OFF_LOSS + 64;         // region zeroed each call
constexpr size_t OFF_LOGMU = ZERO_FLOATS;             // 64*513
constexpr size_t OFF_LOGNU = OFF_LOGMU + 64*513;
constexpr size_t OFF_INVV  = OFF_LOGNU + 64*513;      // 64*512
constexpr size_t OFF_INVT  = OFF_INVV  + 64*512;
constexpr size_t OFF_MASKV = OFF_INVT  + 64*512;      // int 64*512
constexpr size_t OFF_MASKT = OFF_MASKV + 64*512;
constexpr size_t OFF_WV    = OFF_MASKT + 64*512;      // 64*512
constexpr size_t OFF_KH    = OFF_WV    + 64*512;      // half 64*513*520

typedef __attribute__((ext_vector_type(8))) short short8;
typedef __attribute__((ext_vector_type(4))) float floatx4;

__device__ inline ushort f2bf(float f) {          // fp32 -> bf16 RNE
    unsigned u = __float_as_uint(f);
    unsigned r = (u + 0x7FFFu + ((u >> 16) & 1u)) >> 16;
    return (ushort)r;
}

// ---------------- mask dtype detection ----------------
__device__ inline int detect_mode(const unsigned char* p) {
    unsigned char b0 = p[0], b1 = p[1];
    if (b0 == 0) return 2;          // float32 (1.0f -> bytes 00 00 80 3F)
    return (b1 != 0) ? 0 : 1;       // 0: u8/bool, 1: int32
}
__device__ inline int read_mask(const unsigned char* p, long idx, int mode) {
    if (mode == 0) return p[idx] != 0;
    if (mode == 1) return p[4*idx] != 0;
    return ((const float*)p)[idx] != 0.0f;
}

// ---------------- setup: masks, lengths, log_mu/log_nu ----------------
__global__ void setup_kernel(const unsigned char* vm, const unsigned char* tm,
                             float* log_mu, float* log_nu, int* maskv, int* maskt) {
    int b = blockIdx.x;
    bool isV = (blockIdx.y == 0);
    const unsigned char* p = isV ? vm : tm;
    float* lg = isV ? log_mu : log_nu;
    int*   mk = isV ? maskv : maskt;
    int mode = detect_mode(p);
    int i = threadIdx.x;                       // 512 threads
    int m = read_mask(p, (long)b*512 + i, mode);
    mk[b*512 + i] = m;
    float s = (float)m;
    #pragma unroll
    for (int off = 32; off; off >>= 1) s += __shfl_xor(s, off);
    __shared__ float wsum[8];
    int wid = threadIdx.x >> 6, lane = threadIdx.x & 63;
    if (lane == 0) wsum[wid] = s;
    __syncthreads();
    float len = 0.f;
    #pragma unroll
    for (int w = 0; w < 8; ++w) len += wsum[w];
    float lm = m ? __logf(1.0f/(len + 1e-9f) + 1e-9f) : __logf(1e-9f);
    lg[b*NA + i] = lm;
    if (i == 0) lg[b*NA + 512] = 0.0f;         // log(1+1e-9) == 0 in fp32
}

// ---------------- row l2 inverse norms ----------------
__global__ __launch_bounds__(256) void norm_kernel(const float* __restrict__ v,
                                                   const float* __restrict__ t,
                                                   float* invnv, float* invnt) {
    int wid = threadIdx.x >> 6, lane = threadIdx.x & 63;
    long row = (long)blockIdx.x * 4 + wid;        // 0..32767
    const float* src = blockIdx.y ? t : v;
    float* dst = blockIdx.y ? invnt : invnv;
    const float* r = src + row * DIM;
    float ss = 0.f;
    #pragma unroll
    for (int c = 0; c < 3; ++c) {
        float4 x = *(const float4*)(r + (c*64 + lane)*4);
        ss += x.x*x.x + x.y*x.y + x.z*x.z + x.w*x.w;
    }
    #pragma unroll
    for (int off = 32; off; off >>= 1) ss += __shfl_xor(ss, off);
    if (lane == 0) dst[row] = 1.0f / fmaxf(sqrtf(ss), 1e-12f);
}

// ---------------- bf16 MFMA batched GEMM -> K (fp16) ----------------
// 128x128 tile, BK=32, 256 threads (4 waves, 2x2), on-the-fly fp32->bf16.
__global__ __launch_bounds__(256) void gemm_kernel(const float* __restrict__ v,
        const float* __restrict__ t,
        const float* __restrict__ invnv, const float* __restrict__ invnt,
        const int* __restrict__ maskv, const int* __restrict__ maskt,
        __half* __restrict__ K) {
    int bid = blockIdx.x;
    // XCD-aware: all 16 tiles of a batch land on one XCD, temporally adjacent.
    int xcd = bid & 7, kk = bid >> 3;
    int bt   = xcd * 8 + (kk >> 4);
    int tile = kk & 15;
    int m0 = (tile >> 2) * 128, n0 = (tile & 3) * 128;

    __shared__ ushort As[128*40];   // padded stride 40 halves (80B): 2-way max conflicts
    __shared__ ushort Bs[128*40];
    const float* vb = v + (long)bt * NV * DIM;
    const float* tb = t + (long)bt * NT * DIM;
    int tid = threadIdx.x;
    int w = tid >> 6, lane = tid & 63;
    int wm = (w >> 1) * 64, wn = (w & 1) * 64;
    int lrow = lane & 15, khalf = lane >> 4;     // frag: row=lane&15, k=(lane>>4)*8+e

    floatx4 acc[4][4] = {};

    for (int kt = 0; kt < DIM/32; ++kt) {
        int k0 = kt * 32;
        #pragma unroll
        for (int h = 0; h < 4; ++h) {
            int f = tid + h*256;                  // 0..1023
            int row = f >> 3, c4 = (f & 7) * 4;
            float4 a  = *(const float4*)(vb + (long)(m0+row)*DIM + k0 + c4);
            float4 bb = *(const float4*)(tb + (long)(n0+row)*DIM + k0 + c4);
            ushort4 ua = { f2bf(a.x),  f2bf(a.y),  f2bf(a.z),  f2bf(a.w)  };
            ushort4 ub = { f2bf(bb.x), f2bf(bb.y), f2bf(bb.z), f2bf(bb.w) };
            *(ushort4*)&As[row*40 + c4] = ua;
            *(ushort4*)&Bs[row*40 + c4] = ub;
        }
        __syncthreads();
        short8 af[4], bf[4];
        #pragma unroll
        for (int mi = 0; mi < 4; ++mi)
            af[mi] = *(const short8*)&As[(wm + mi*16 + lrow)*40 + khalf*8];
        #pragma unroll
        for (int nj = 0; nj < 4; ++nj)
            bf[nj] = *(const short8*)&Bs[(wn + nj*16 + lrow)*40 + khalf*8];
        #pragma unroll
        for (int mi = 0; mi < 4; ++mi)
            #pragma unroll
            for (int nj = 0; nj < 4; ++nj)
                acc[mi][nj] = __builtin_amdgcn_mfma_f32_16x16x32_bf16(
                                  af[mi], bf[nj], acc[mi][nj], 0, 0, 0);
        __syncthreads();
    }

    const float* invnv_b = invnv + bt*NV;
    const float* invnt_b = invnt + bt*NT;
    const int*   maskv_b = maskv + bt*NV;
    const int*   maskt_b = maskt + bt*NT;
    __half* Kb = K + (long)bt * KBATCH_H;
    int col = lane & 15, rq = lane >> 4;          // C/D: col=lane&15, row=(lane>>4)*4+r
    #pragma unroll
    for (int nj = 0; nj < 4; ++nj) {
        int gn = n0 + wn + nj*16 + col;
        float sn = invnt_b[gn] * INV_EPS;
        bool  mn = maskt_b[gn] != 0;
        #pragma unroll
        for (int mi = 0; mi < 4; ++mi) {
            #pragma unroll
            for (int r = 0; r < 4; ++r) {
                int gm = m0 + wm + mi*16 + rq*4 + r;
                float val = acc[mi][nj][r] * invnv_b[gm] * sn;
                bool ok = mn && (maskv_b[gm] != 0);
                Kb[(long)gm * KP_H + gn] = __float2half(ok ? val : NEG_KH);
            }
        }
    }
}

// ---------------- gamma row/col fill: K = GAMMA/EPS = 1.0 ----------------
__global__ void fill_gamma(__half* K) {
    int b = blockIdx.x;
    __half* Kb = K + (long)b * KBATCH_H;
    __half one = __float2half(1.0f);
    for (int i = threadIdx.x; i < NA; i += blockDim.x) {
        Kb[(long)512*KP_H + i] = one;
        Kb[(long)i*KP_H + 512] = one;
    }
}

// ---------------- Sinkhorn row pass: u = log_mu - lse_j(K + vv) ----------------
// Two-phase per-row LSE: 8 values in regs -> max tree -> exp sum; no serial chain.
__global__ __launch_bounds__(256) void row_pass(const __half* __restrict__ K,
        const float* __restrict__ vvg, const float* __restrict__ log_mu, float* u) {
    int b = blockIdx.y;
    __shared__ float vvs[NA];
    for (int idx = threadIdx.x; idx < NA; idx += 256) vvs[idx] = vvg[b*NA + idx];
    __syncthreads();
    int w = threadIdx.x >> 6, lane = threadIdx.x & 63;
    const __half* Kb = K + (long)b * KBATCH_H;
    for (int r = 0; r < 4; ++r) {
        int i = blockIdx.x * 16 + w * 4 + r;
        if (i >= NA) break;
        const __half* Krow = Kb + (long)i * KP_H;
        float x[8];
        #pragma unroll
        for (int c = 0; c < 4; ++c) {
            int j = c*128 + lane*2;
            __half2 h2 = *(const __half2*)(Krow + j);
            x[2*c]   = __low2float(h2)  + vvs[j];
            x[2*c+1] = __high2float(h2) + vvs[j+1];
        }
        float x8 = (lane == 0) ? (__half2float(Krow[512]) + vvs[512]) : -1e30f;
        float m = fmaxf(fmaxf(fmaxf(x[0],x[1]), fmaxf(x[2],x[3])),
                        fmaxf(fmaxf(x[4],x[5]), fmaxf(x[6],x[7])));
        m = fmaxf(m, x8);
        float s = 0.f;
        #pragma unroll
        for (int q = 0; q < 8; ++q) s += __expf(x[q] - m);
        if (lane == 0) s += __expf(x8 - m);
        #pragma unroll
        for (int off = 32; off; off >>= 1) {
            float m2 = __shfl_xor(m, off), s2 = __shfl_xor(s, off);
            float nm = fmaxf(m, m2);
            s = s*__expf(m - nm) + s2*__expf(m2 - nm);
            m = nm;
        }
        if (lane == 0) u[b*NA + i] = log_mu[b*NA + i] - (m + __logf(s));
    }
}

// ---------------- Sinkhorn col pass: vv = log_nu - lse_i(K + u) ----------------
// 4 waves x 64 cols; rows split across waves; chunked two-phase LSE; LDS merge.
__global__ __launch_bounds__(256) void col_pass(const __half* __restrict__ K,
        const float* __restrict__ ug, const float* __restrict__ log_nu, float* vv) {
    int b = blockIdx.y;
    __shared__ float us[NA];
    __shared__ float mp[4][64], sp[4][64];
    for (int idx = threadIdx.x; idx < NA; idx += 256) us[idx] = ug[b*NA + idx];
    __syncthreads();
    int w = threadIdx.x >> 6, lane = threadIdx.x & 63;
    int j = blockIdx.x * 64 + lane;               // grid.x = 9; block 8 covers col 512
    bool active = (j < NA);
    const __half* Kb = K + (long)b * KBATCH_H;
    int i0 = w * 129;
    int i1 = min(NA, i0 + 129);
    float m = -1e30f, s = 0.0f;
    if (active) {
        int i = i0;
        for (; i + 8 <= i1; i += 8) {
            float x[8];
            #pragma unroll
            for (int q = 0; q < 8; ++q)
                x[q] = __half2float(Kb[(long)(i+q)*KP_H + j]) + us[i+q];
            float cm = fmaxf(fmaxf(fmaxf(x[0],x[1]), fmaxf(x[2],x[3])),
                             fmaxf(fmaxf(x[4],x[5]), fmaxf(x[6],x[7])));
            float nm = fmaxf(m, cm);
            float cs = 0.f;
            #pragma unroll
            for (int q = 0; q < 8; ++q) cs += __expf(x[q] - nm);
            s = s * __expf(m - nm) + cs;
            m = nm;
        }
        for (; i < i1; ++i) {
            float x = __half2float(Kb[(long)i*KP_H + j]) + us[i];
            float nm = fmaxf(m, x);
            s = s*__expf(m - nm) + __expf(x - nm);
            m = nm;
        }
    }
    mp[w][lane] = m; sp[w][lane] = s;
    __syncthreads();
    if (w == 0 && active) {
        float M = mp[0][lane], S = sp[0][lane];
        #pragma unroll
        for (int ww = 1; ww < 4; ++ww) {
            float m2 = mp[ww][lane], s2 = sp[ww][lane];
            float nm = fmaxf(M, m2);
            S = S*__expf(M - nm) + s2*__expf(m2 - nm);
            M = nm;
        }
        vv[b*NA + j] = log_nu[b*NA + j] - (M + __logf(S));
    }
}

// ---------------- final: T*, loss, row/col sums of relu(T - tau) ----------------
__global__ __launch_bounds__(256) void final_kernel(const __half* __restrict__ K,
        const float* __restrict__ u, const float* __restrict__ vvg,
        float* w_v_num, float* w_t_num, float* loss_sum) {
    int b = blockIdx.y;
    __shared__ float vvs[NA];
    __shared__ float colsum[NT];
    __shared__ float lw[4];
    for (int idx = threadIdx.x; idx < NA; idx += 256) vvs[idx] = vvg[b*NA + idx];
    for (int idx = threadIdx.x; idx < NT; idx += 256) colsum[idx] = 0.f;
    __syncthreads();
    int w = threadIdx.x >> 6, lane = threadIdx.x & 63;
    const __half* Kb = K + (long)b * KBATCH_H;
    float creg[8] = {0,0,0,0,0,0,0,0};
    float lossacc = 0.f;
    for (int r = 0; r < 16; ++r) {
        int i = blockIdx.x*64 + w*16 + r;
        if (i >= NA) break;
        float ui = u[b*NA + i];
        const __half* Krow = Kb + (long)i * KP_H;
        bool realrow = (i < NV);
        float rowacc = 0.f;
        #pragma unroll
        for (int c = 0; c < 4; ++c) {
            int j = c*128 + lane*2;
            __half2 h2 = *(const __half2*)(Krow + j);
            float k0 = __low2float(h2), k1 = __high2float(h2);
            float t0 = __expf(ui + vvs[j]   + k0);
            float t1 = __expf(ui + vvs[j+1] + k1);
            lossacc += t0*(1.f - EPS_OT*k0) + t1*(1.f - EPS_OT*k1);
            if (realrow) {
                float th0 = fmaxf(t0 - TAU_OT, 0.f);
                float th1 = fmaxf(t1 - TAU_OT, 0.f);
                rowacc += th0 + th1;
                creg[2*c] += th0; creg[2*c+1] += th1;
            }
        }
        if (lane == 0) {                           // gamma column j=512: loss only
            float kg = __half2float(Krow[512]);
            float tg = __expf(ui + vvs[512] + kg);
            lossacc += tg*(1.f - EPS_OT*kg);
        }
        #pragma unroll
        for (int off = 32; off; off >>= 1) rowacc += __shfl_xor(rowacc, off);
        if (realrow && lane == 0) w_v_num[b*NV + i] = rowacc + DELTA_OT;
    }
    #pragma unroll
    for (int c = 0; c < 4; ++c) {
        atomicAdd(&colsum[c*128 + lane*2    ], creg[2*c]);
        atomicAdd(&colsum[c*128 + lane*2 + 1], creg[2*c+1]);
    }
    __syncthreads();
    for (int idx = threadIdx.x; idx < NT; idx += 256)
        atomicAdd(&w_t_num[b*NT + idx], colsum[idx]);
    #pragma unroll
    for (int off = 32; off; off >>= 1) lossacc += __shfl_xor(lossacc, off);
    if (lane == 0) lw[w] = lossacc;
    __syncthreads();
    if (threadIdx.x == 0) atomicAdd(loss_sum, lw[0]+lw[1]+lw[2]+lw[3]);
}

// ---------------- normalize w vectors ----------------
__global__ void wnorm_kernel(const float* num, float* out, float addd) {
    int b = blockIdx.x;
    float v = num[b*512 + threadIdx.x] + addd;
    float s = v;
    #pragma unroll
    for (int off = 32; off; off >>= 1) s += __shfl_xor(s, off);
    __shared__ float wsum[8];
    int wid = threadIdx.x >> 6, lane = threadIdx.x & 63;
    if (lane == 0) wsum[wid] = s;
    __syncthreads();
    float tot = 0.f;
    #pragma unroll
    for (int w = 0; w < 8; ++w) tot += wsum[w];
    out[b*512 + threadIdx.x] = v / tot;
}

__global__ void loss_kernel(const float* loss_sum, float* out) {
    out[0] = loss_sum[0] * (1.0f / 64.0f);
}

// ---------------- launch ----------------
extern "C" void kernel_launch(void* const* d_in, const int* in_sizes, int n_in,
                              void* d_out, int out_size, void* d_ws, size_t ws_size,
                              hipStream_t stream) {
    const float* v = (const float*)d_in[0];
    const float* t = (const float*)d_in[1];
    const unsigned char* vm = (const unsigned char*)d_in[2];
    const unsigned char* tm = (const unsigned char*)d_in[3];
    float* ws  = (float*)d_ws;
    float* out = (float*)d_out;

    float* U     = ws + OFF_U;
    float* VVv   = ws + OFF_VV;
    float* WT    = ws + OFF_WT;
    float* LOSS  = ws + OFF_LOSS;
    float* LOGMU = ws + OFF_LOGMU;
    float* LOGNU = ws + OFF_LOGNU;
    float* INVV  = ws + OFF_INVV;
    float* INVT  = ws + OFF_INVT;
    int*   MASKV = (int*)(ws + OFF_MASKV);
    int*   MASKT = (int*)(ws + OFF_MASKT);
    float* WV    = ws + OFF_WV;
    __half* Kmat = (__half*)(ws + OFF_KH);

    hipMemsetAsync(ws, 0, ZERO_FLOATS * sizeof(float), stream);

    setup_kernel<<<dim3(BB, 2), 512, 0, stream>>>(vm, tm, LOGMU, LOGNU, MASKV, MASKT);
    norm_kernel<<<dim3(BB*NV/4, 2), 256, 0, stream>>>(v, t, INVV, INVT);
    gemm_kernel<<<dim3(1024), 256, 0, stream>>>(v, t, INVV, INVT, MASKV, MASKT, Kmat);
    fill_gamma<<<BB, 256, 0, stream>>>(Kmat);

    for (int it = 0; it < 5; ++it) {
        row_pass<<<dim3(33, BB), 256, 0, stream>>>(Kmat, VVv, LOGMU, U);
        col_pass<<<dim3(9, BB), 256, 0, stream>>>(Kmat, U, LOGNU, VVv);
    }

    final_kernel<<<dim3(9, BB), 256, 0, stream>>>(Kmat, U, VVv, WV, WT, LOSS);
    wnorm_kernel<<<BB, 512, 0, stream>>>(WV, out + 1, 0.0f);
    wnorm_kernel<<<BB, 512, 0, stream>>>(WT, out + 1 + BB*NV, DELTA_OT);
    loss_kernel<<<1, 1, 0, stream>>>(LOSS, out);
}